// Round 9
// baseline (1936.317 us; speedup 1.0000x reference)
//
#include <hip/hip_runtime.h>
#include <hip/hip_bf16.h>
#include <stdint.h>

#define S 2048
#define D 64
#define BH 32
#define NROWS (BH * S)              // 65536
#define CTX_ELEMS (NROWS * D)
#define RPB 4                       // rows per block (1 per wave)
#define NPB (NROWS / RPB)           // 16384 blocks
#define TROWS 64                    // tile rows (adoption unit)
#define BPT (TROWS / RPB)           // 16 blocks per tile
#define NTILES (NROWS / TROWS)      // 1024

typedef __attribute__((ext_vector_type(8))) __bf16 bf16x8;
typedef __attribute__((ext_vector_type(4))) float f32x4;
typedef __attribute__((ext_vector_type(4))) int   i32x4;

// Single dispatch. Block b: PRODUCE rows [b*4, b*4+4) (wave-per-row, sync-free
// R8 body: attn row + packed word into ctx-alias). Then one ACQ_REL atomic on
// the 64-row tile counter; the 16th arrival ADOPTS the tile and runs the
// consumer GEMM (ctx = inv * bits @ V) under the still-running stream.
// No spinning, no convoy; deadlock-free (no waits anywhere).
__global__ __launch_bounds__(256) void k_all(const int* __restrict__ mask,
                                             const float* __restrict__ V,
                                             float* ctx,
                                             float* __restrict__ attn,
                                             int* __restrict__ tilecnt) {
  const int t = threadIdx.x;
  const int lane = t & 63;
  const int w = t >> 6;             // wave 0..3

  __shared__ uint32_t pk[TROWS * 65];   // consumer: byte stride 260 (bank-free)
  __shared__ float invs[TROWS];
  __shared__ int adopt;

  uint32_t* packedG = (uint32_t*)ctx;   // 16.8 MB alias, tile-local lifetime

  // ================= PRODUCER: one row per wave =================
  {
    const int row = blockIdx.x * RPB + w;
    const int* mrow = mask + (long)row * S;

    uint32_t nib = 0;
#pragma unroll
    for (int j = 0; j < 8; ++j) {
      const i32x4 m = __builtin_nontemporal_load(
          (const i32x4*)(mrow + j * 256 + lane * 4));
      nib |= (m[0] == 0 ? 1u : 0u) << (j * 4);
      nib |= (m[1] == 0 ? 1u : 0u) << (j * 4 + 1);
      nib |= (m[2] == 0 ? 1u : 0u) << (j * 4 + 2);
      nib |= (m[3] == 0 ? 1u : 0u) << (j * 4 + 3);
    }

    int cnt = __popc(nib);
#pragma unroll
    for (int off = 1; off < 64; off <<= 1) cnt += __shfl_xor(cnt, off, 64);
    const float inv = (cnt > 0) ? (1.0f / (float)cnt) : 0.0f;

    float* arow = attn + (long)row * S;
#pragma unroll
    for (int j = 0; j < 8; ++j) {
      f32x4 a;
      a[0] = ((nib >> (j * 4)) & 1u)     ? inv : 0.0f;
      a[1] = ((nib >> (j * 4 + 1)) & 1u) ? inv : 0.0f;
      a[2] = ((nib >> (j * 4 + 2)) & 1u) ? inv : 0.0f;
      a[3] = ((nib >> (j * 4 + 3)) & 1u) ? inv : 0.0f;
      __builtin_nontemporal_store(a, (f32x4*)(arow + j * 256 + lane * 4));
    }

    // packed word l: bit i = nibble bit (i&3) of group (l>>3) from lane (l&7)*8+(i>>2)
    uint32_t word = 0;
    const int jsel = 4 * (lane >> 3);
    const int lbase = (lane & 7) * 8;
#pragma unroll
    for (int d = 0; d < 8; ++d) {
      const uint32_t nw = (uint32_t)__shfl((int)nib, lbase + d, 64);
      word |= ((nw >> jsel) & 0xFu) << (4 * d);
    }
    packedG[(long)row * 64 + lane] = word;
  }

  // ================= ADOPTION =================
  const int tile = blockIdx.x / BPT;
  __syncthreads();                        // all 4 waves' stores vmcnt-drained
  if (t == 0) {
    __threadfence();                      // make them agent-visible (release side)
    const int old = __hip_atomic_fetch_add(&tilecnt[tile], 1,
                                           __ATOMIC_ACQ_REL,
                                           __HIP_MEMORY_SCOPE_AGENT);
    adopt = (old == BPT - 1) ? 1 : 0;
  }
  __syncthreads();
  if (!adopt) return;

  // ================= CONSUMER: tile GEMM (64 rows) =================
  const long R0 = (long)tile * TROWS;     // global row base
  const int bh = tile >> 5;               // tile/(S/TROWS)
  const int l15 = lane & 15;
  const int lk = lane >> 4;               // 0..3

  for (int i = t; i < TROWS * 64; i += 256)
    pk[(i >> 6) * 65 + (i & 63)] = packedG[(R0 + (i >> 6)) * 64 + (i & 63)];
  __syncthreads();

  if (t < TROWS) {
    int c = 0;
#pragma unroll
    for (int i = 0; i < 64; ++i) c += __popc(pk[t * 65 + i]);
    invs[t] = (c > 0) ? (1.0f / (float)c) : 0.0f;
  }
  __syncthreads();

  // wave w: rows [w*16, w*16+16) (one m-tile), N=64
  const uint8_t* pkb = (const uint8_t*)pk;
  const uint8_t* ap = pkb + (w * 16 + l15) * 260 + lk;
  const float* vf0 = V + (long)bh * S * D + (long)lk * 8 * D + l15;

  f32x4 acc[4];
#pragma unroll
  for (int n4 = 0; n4 < 4; ++n4) acc[n4] = f32x4{0.f, 0.f, 0.f, 0.f};

  float cur[32], nxt[32];
  auto LOADB = [&](float* dst, int kk) {
    const float* vp = vf0 + (long)kk * 32 * D;
#pragma unroll
    for (int n4 = 0; n4 < 4; ++n4)
#pragma unroll
      for (int j = 0; j < 8; ++j)
        dst[n4 * 8 + j] = vp[j * D + n4 * 16];
  };
  auto COMPUTE = [&](const float* buf, int kk) {
    bf16x8 bf[4];
#pragma unroll
    for (int n4 = 0; n4 < 4; ++n4) {
      bf16x8 x;
#pragma unroll
      for (int j = 0; j < 8; ++j) x[j] = (__bf16)buf[n4 * 8 + j];
      bf[n4] = x;
    }
    const uint32_t by = ap[kk * 4];
    union { uint32_t u[4]; bf16x8 v; } am;
#pragma unroll
    for (int p = 0; p < 4; ++p) {
      am.u[p] = (((by >> (2 * p)) & 1u) ? 0x3F80u : 0u)
              | (((by >> (2 * p + 1)) & 1u) ? 0x3F800000u : 0u);
    }
#pragma unroll
    for (int n4 = 0; n4 < 4; ++n4)
      acc[n4] = __builtin_amdgcn_mfma_f32_16x16x32_bf16(am.v, bf[n4], acc[n4], 0, 0, 0);
  };

  LOADB(cur, 0);
#pragma unroll 1
  for (int kk = 0; kk < S / 32; kk += 2) {
    LOADB(nxt, kk + 1);
    COMPUTE(cur, kk);
    if (kk + 2 < S / 32) LOADB(cur, kk + 2);
    COMPUTE(nxt, kk + 1);
  }

  // epilogue: C/D layout col=l15, row=lk*4+ri (m89-verified)
#pragma unroll
  for (int ri = 0; ri < 4; ++ri) {
    const int rloc = w * 16 + lk * 4 + ri;
    const float iv = invs[rloc];
    const long orow = R0 + rloc;
#pragma unroll
    for (int n4 = 0; n4 < 4; ++n4)
      ctx[orow * D + n4 * 16 + l15] = acc[n4][ri] * iv;
  }
}

extern "C" void kernel_launch(void* const* d_in, const int* in_sizes, int n_in,
                              void* d_out, int out_size, void* d_ws, size_t ws_size,
                              hipStream_t stream) {
  (void)in_sizes; (void)n_in; (void)out_size; (void)ws_size;
  const float* V = (const float*)d_in[2];           // Q,K provably unused (mask overwrites all scores)
  const int* mask = (const int*)d_in[3];
  float* ctx = (float*)d_out;                       // output 0: [B,H,S,D]
  float* attn = (float*)d_out + (size_t)CTX_ELEMS;  // output 1: [B,H,S,S]
  int* tilecnt = (int*)d_ws;                        // NTILES ints (4 KB)

  hipMemsetAsync(tilecnt, 0, NTILES * sizeof(int), stream);
  k_all<<<NPB, 256, 0, stream>>>(mask, V, ctx, attn, tilecnt);
}

// Round 10
// 302.556 us; speedup vs baseline: 6.3999x; 6.3999x over previous
//
#include <hip/hip_runtime.h>
#include <hip/hip_bf16.h>
#include <stdint.h>

#define S 2048
#define D 64
#define BH 32
#define NROWS (BH * S)              // 65536
#define CTX_ELEMS (NROWS * D)
#define NVTB 512                    // VT rider blocks
#define NSTB 2048                   // stream blocks (4 waves each)
#define WSTRIDE (NSTB * 4)          // 8192 waves -> 8 rows per wave
#define VT_BYTES ((size_t)BH * 64 * 64 * 32 * 2)   // 8.4 MB tiled bf16 V^T

typedef __attribute__((ext_vector_type(8))) __bf16 bf16x8;
typedef __attribute__((ext_vector_type(4))) float f32x4;
typedef __attribute__((ext_vector_type(4))) int   i32x4;

// VT32 layout: VT32[bh][kk][c][k']  (kk=k/32, c=col 0..63, k'=k%32); B-frag for
// step kk = one bf16x8; a wave's 64 lanes cover a contiguous 1KB per n4-tile.

// ---------- Kernel 1: wave-per-row stream, 2-deep row pipeline ----------
// Plain (cached) mask loads; nontemporal attn stores. Next row's 8 loads are
// issued before the current row's reduce+store phase -> HBM latency hidden
// under compute/store issue. No LDS, no __syncthreads, no atomics.
__global__ __launch_bounds__(256, 8) void k_mask(const int* __restrict__ mask,
                                                 const float* __restrict__ V,
                                                 float* __restrict__ attn,
                                                 uint32_t* __restrict__ packed,
                                                 __bf16* __restrict__ VT,
                                                 int use_vt) {
  const int t = threadIdx.x;

  if (blockIdx.x < NVTB) {
    if (!use_vt) return;
    // ---- VT rider (R7-proven): bh = b>>4, kk in [(b&15)*4, +4) ----
    const int bh = blockIdx.x >> 4;
    const int kk0 = (blockIdx.x & 15) * 4;
    const int c = t >> 2;
    const int g = t & 3;
#pragma unroll
    for (int s = 0; s < 4; ++s) {
      const int kk = kk0 + s;
      const float* vp = V + ((long)bh * S + kk * 32 + g * 8) * D + c;
      bf16x8 o;
#pragma unroll
      for (int j = 0; j < 8; ++j) o[j] = (__bf16)vp[(long)j * D];
      *reinterpret_cast<bf16x8*>(VT + (((long)bh * 64 + kk) * 64 + c) * 32 + g * 8) = o;
    }
    return;
  }

  const int lane = t & 63;
  const int W = (blockIdx.x - NVTB) * 4 + (t >> 6);   // wave id 0..8191

  i32x4 m[8];
  {
    const int* mr = mask + (long)W * S;
#pragma unroll
    for (int j = 0; j < 8; ++j)
      m[j] = *(const i32x4*)(mr + j * 256 + lane * 4);
  }

#pragma unroll 1
  for (int row = W; row < NROWS; row += WSTRIDE) {
    // consume current row's loads -> nibble word
    uint32_t nib = 0;
#pragma unroll
    for (int j = 0; j < 8; ++j) {
      nib |= (m[j][0] == 0 ? 1u : 0u) << (j * 4);
      nib |= (m[j][1] == 0 ? 1u : 0u) << (j * 4 + 1);
      nib |= (m[j][2] == 0 ? 1u : 0u) << (j * 4 + 2);
      nib |= (m[j][3] == 0 ? 1u : 0u) << (j * 4 + 3);
    }

    // prefetch next row NOW (overlaps reduce+stores below)
    const int nrow = row + WSTRIDE;
    if (nrow < NROWS) {
      const int* mr = mask + (long)nrow * S;
#pragma unroll
      for (int j = 0; j < 8; ++j)
        m[j] = *(const i32x4*)(mr + j * 256 + lane * 4);
    }

    int cnt = __popc(nib);
#pragma unroll
    for (int off = 1; off < 64; off <<= 1) cnt += __shfl_xor(cnt, off, 64);
    const float inv = (cnt > 0) ? (1.0f / (float)cnt) : 0.0f;

    float* arow = attn + (long)row * S;
#pragma unroll
    for (int j = 0; j < 8; ++j) {
      f32x4 a;
      a[0] = ((nib >> (j * 4)) & 1u)     ? inv : 0.0f;
      a[1] = ((nib >> (j * 4 + 1)) & 1u) ? inv : 0.0f;
      a[2] = ((nib >> (j * 4 + 2)) & 1u) ? inv : 0.0f;
      a[3] = ((nib >> (j * 4 + 3)) & 1u) ? inv : 0.0f;
      __builtin_nontemporal_store(a, (f32x4*)(arow + j * 256 + lane * 4));
    }

    // packed word l: bit i = nibble bit (i&3) of group (l>>3) from lane (l&7)*8+(i>>2)
    uint32_t word = 0;
    const int jsel = 4 * (lane >> 3);
    const int lbase = (lane & 7) * 8;
#pragma unroll
    for (int d = 0; d < 8; ++d) {
      const uint32_t nw = (uint32_t)__shfl((int)nib, lbase + d, 64);
      word |= ((nw >> jsel) & 0xFu) << (4 * d);
    }
    packed[(long)row * 64 + lane] = word;
  }
}

// ---------- Kernel 2 (R8-verbatim): ctx = inv * (bits @ V), BMC=64 ----------
#define BMC 64
template<bool USE_VT>
__global__ __launch_bounds__(128) void k_ctx(const uint32_t* __restrict__ packed,
                                             const float* __restrict__ V,
                                             const __bf16* __restrict__ VT,
                                             float* __restrict__ ctx) {
  const int flat = blockIdx.x;
  const int wid = (flat & 7) * ((NROWS / BMC) / 8) + (flat >> 3);
  const int qt = wid & 31;
  const int bh = wid >> 5;

  const int t = threadIdx.x;
  const int lane = t & 63;
  const int w = t >> 6;               // wave 0..1, rows [w*32, w*32+32)
  const int l15 = lane & 15;
  const int lk = lane >> 4;           // 0..3

  __shared__ uint32_t pk[BMC * 65];   // byte stride 260 -> bank stride 1
  __shared__ float invs[BMC];

  const long R0 = (long)bh * S + (long)qt * BMC;

  for (int i = t; i < BMC * 64; i += 128)
    pk[(i >> 6) * 65 + (i & 63)] = packed[(R0 + (i >> 6)) * 64 + (i & 63)];
  __syncthreads();

  if (t < BMC) {
    int c = 0;
#pragma unroll
    for (int i = 0; i < 64; ++i) c += __popc(pk[t * 65 + i]);
    invs[t] = (c > 0) ? (1.0f / (float)c) : 0.0f;
  }
  __syncthreads();

  const uint8_t* pkb = (const uint8_t*)pk;
  const uint8_t* ap[2];
#pragma unroll
  for (int mt = 0; mt < 2; ++mt)
    ap[mt] = pkb + (w * 32 + mt * 16 + l15) * 260 + lk;
  const __bf16* vt0 = VT + ((long)bh * 64) * 64 * 32 + (long)l15 * 32 + lk * 8;
  const float* vf0 = V + (long)bh * S * D + (long)lk * 8 * D + l15;

  f32x4 acc[2][4];
#pragma unroll
  for (int a = 0; a < 2; ++a)
#pragma unroll
    for (int b = 0; b < 4; ++b) acc[a][b] = f32x4{0.f, 0.f, 0.f, 0.f};

  auto LOADB = [&](bf16x8* dst, uint32_t* by, int kk) {
    if (USE_VT) {
#pragma unroll
      for (int n4 = 0; n4 < 4; ++n4)
        dst[n4] = *reinterpret_cast<const bf16x8*>(vt0 + ((long)kk * 64 + n4 * 16) * 32);
    } else {
      const float* vp = vf0 + (long)kk * 32 * D;
#pragma unroll
      for (int n4 = 0; n4 < 4; ++n4) {
        bf16x8 x;
#pragma unroll
        for (int j = 0; j < 8; ++j) x[j] = (__bf16)vp[j * D + n4 * 16];
        dst[n4] = x;
      }
    }
#pragma unroll
    for (int mt = 0; mt < 2; ++mt) by[mt] = ap[mt][kk * 4];
  };

  auto COMPUTE = [&](const bf16x8* bf, const uint32_t* by) {
#pragma unroll
    for (int mt = 0; mt < 2; ++mt) {
      union { uint32_t u[4]; bf16x8 v; } am;
#pragma unroll
      for (int p = 0; p < 4; ++p) {
        am.u[p] = (((by[mt] >> (2 * p)) & 1u) ? 0x3F80u : 0u)
                | (((by[mt] >> (2 * p + 1)) & 1u) ? 0x3F800000u : 0u);
      }
#pragma unroll
      for (int n4 = 0; n4 < 4; ++n4)
        acc[mt][n4] = __builtin_amdgcn_mfma_f32_16x16x32_bf16(am.v, bf[n4], acc[mt][n4], 0, 0, 0);
    }
  };

  bf16x8 bA[4], bB[4];
  uint32_t byA[2], byB[2];
  LOADB(bA, byA, 0);
#pragma unroll 1
  for (int kk = 0; kk < S / 32; kk += 2) {
    LOADB(bB, byB, kk + 1);
    COMPUTE(bA, byA);
    if (kk + 2 < S / 32) LOADB(bA, byA, kk + 2);
    COMPUTE(bB, byB);
  }

  // epilogue: C/D layout col=l15, row=lk*4+ri (m89-verified)
#pragma unroll
  for (int mt = 0; mt < 2; ++mt) {
#pragma unroll
    for (int ri = 0; ri < 4; ++ri) {
      const int rloc = w * 32 + mt * 16 + lk * 4 + ri;
      const float iv = invs[rloc];
      const long orow = R0 + rloc;
#pragma unroll
      for (int n4 = 0; n4 < 4; ++n4)
        ctx[orow * D + n4 * 16 + l15] = acc[mt][n4][ri] * iv;
    }
  }
}

extern "C" void kernel_launch(void* const* d_in, const int* in_sizes, int n_in,
                              void* d_out, int out_size, void* d_ws, size_t ws_size,
                              hipStream_t stream) {
  (void)in_sizes; (void)n_in; (void)out_size;
  const float* V = (const float*)d_in[2];           // Q,K provably unused (mask overwrites all scores)
  const int* mask = (const int*)d_in[3];
  float* ctx = (float*)d_out;                       // output 0: [B,H,S,D]
  float* attn = (float*)d_out + (size_t)CTX_ELEMS;  // output 1: [B,H,S,S]
  uint32_t* packed = (uint32_t*)d_out;              // scratch aliasing ctx region (tile-local)
  __bf16* VT = (__bf16*)d_ws;

  const int use_vt = (ws_size >= VT_BYTES) ? 1 : 0;
  k_mask<<<NVTB + NSTB, 256, 0, stream>>>(mask, V, attn, packed, VT, use_vt);
  if (use_vt)
    k_ctx<true><<<NROWS / BMC, 128, 0, stream>>>(packed, V, VT, ctx);
  else
    k_ctx<false><<<NROWS / BMC, 128, 0, stream>>>(packed, V, VT, ctx);
}

// Round 11
// 301.822 us; speedup vs baseline: 6.4154x; 1.0024x over previous
//
#include <hip/hip_runtime.h>
#include <hip/hip_bf16.h>
#include <stdint.h>

#define S 2048
#define D 64
#define BH 32
#define NROWS (BH * S)              // 65536
#define CTX_ELEMS (NROWS * D)
#define NVTB 512                    // VT rider blocks
#define NSTB 2048                   // stream blocks (grid-stride, 4 waves each)
#define VT_BYTES ((size_t)BH * 64 * 64 * 32 * 2)   // 8.4 MB tiled bf16 V^T

typedef __attribute__((ext_vector_type(8))) __bf16 bf16x8;
typedef __attribute__((ext_vector_type(4))) float f32x4;
typedef __attribute__((ext_vector_type(4))) int   i32x4;

// ---------- Kernel 1 (R8-VERBATIM): wave-per-row stream + VT riders ----------
__global__ __launch_bounds__(256) void k_mask(const int* __restrict__ mask,
                                              const float* __restrict__ V,
                                              float* __restrict__ attn,
                                              uint32_t* __restrict__ packed,
                                              __bf16* __restrict__ VT,
                                              int use_vt) {
  const int t = threadIdx.x;

  if (blockIdx.x < NVTB) {
    if (!use_vt) return;
    const int bh = blockIdx.x >> 4;
    const int kk0 = (blockIdx.x & 15) * 4;
    const int c = t >> 2;
    const int g = t & 3;
#pragma unroll
    for (int s = 0; s < 4; ++s) {
      const int kk = kk0 + s;
      const float* vp = V + ((long)bh * S + kk * 32 + g * 8) * D + c;
      bf16x8 o;
#pragma unroll
      for (int j = 0; j < 8; ++j) o[j] = (__bf16)vp[(long)j * D];
      *reinterpret_cast<bf16x8*>(VT + (((long)bh * 64 + kk) * 64 + c) * 32 + g * 8) = o;
    }
    return;
  }

  const int lane = t & 63;
  const int W = (blockIdx.x - NVTB) * 4 + (t >> 6);   // global wave id 0..8191

#pragma unroll 1
  for (int row = W; row < NROWS; row += NSTB * 4) {
    const int* mrow = mask + (long)row * S;

    uint32_t nib = 0;
#pragma unroll
    for (int j = 0; j < 8; ++j) {
      const i32x4 m = __builtin_nontemporal_load(
          (const i32x4*)(mrow + j * 256 + lane * 4));
      nib |= (m[0] == 0 ? 1u : 0u) << (j * 4);
      nib |= (m[1] == 0 ? 1u : 0u) << (j * 4 + 1);
      nib |= (m[2] == 0 ? 1u : 0u) << (j * 4 + 2);
      nib |= (m[3] == 0 ? 1u : 0u) << (j * 4 + 3);
    }

    int cnt = __popc(nib);
#pragma unroll
    for (int off = 1; off < 64; off <<= 1) cnt += __shfl_xor(cnt, off, 64);
    const float inv = (cnt > 0) ? (1.0f / (float)cnt) : 0.0f;

    float* arow = attn + (long)row * S;
#pragma unroll
    for (int j = 0; j < 8; ++j) {
      f32x4 a;
      a[0] = ((nib >> (j * 4)) & 1u)     ? inv : 0.0f;
      a[1] = ((nib >> (j * 4 + 1)) & 1u) ? inv : 0.0f;
      a[2] = ((nib >> (j * 4 + 2)) & 1u) ? inv : 0.0f;
      a[3] = ((nib >> (j * 4 + 3)) & 1u) ? inv : 0.0f;
      __builtin_nontemporal_store(a, (f32x4*)(arow + j * 256 + lane * 4));
    }

    uint32_t word = 0;
    const int jsel = 4 * (lane >> 3);
    const int lbase = (lane & 7) * 8;
#pragma unroll
    for (int d = 0; d < 8; ++d) {
      const uint32_t nw = (uint32_t)__shfl((int)nib, lbase + d, 64);
      word |= ((nw >> jsel) & 0xFu) << (4 * d);
    }
    packed[(long)row * 64 + lane] = word;
  }
}

// ---------- Kernel 2: ctx = inv*(bits @ V), K-SPLIT across 4 waves ----------
// 64-row tile/block, 256 thr. Wave w computes K range [w*512,(w+1)*512)
// (16 MFMA steps, 4x shallower serial chain), partial acc -> LDS f32
// reduction (ds_add_f32) -> cooperative scaled write. 1024 blocks, 33KB LDS.
#define BMC 64
template<bool USE_VT>
__global__ __launch_bounds__(256) void k_ctx(const uint32_t* __restrict__ packed,
                                             const float* __restrict__ V,
                                             const __bf16* __restrict__ VT,
                                             float* __restrict__ ctx) {
  // XCD swizzle: each XCD owns 4 whole (b,h) -> V/VT panel L2-resident
  const int flat = blockIdx.x;
  const int wid = (flat & 7) * ((NROWS / BMC) / 8) + (flat >> 3);
  const int qt = wid & 31;
  const int bh = wid >> 5;

  const int t = threadIdx.x;
  const int lane = t & 63;
  const int w = t >> 6;               // wave 0..3 -> K-quarter
  const int l15 = lane & 15;
  const int lk = lane >> 4;           // 0..3

  __shared__ uint32_t pk[BMC * 65];   // byte stride 260 -> bank stride 1
  __shared__ float invs[BMC];
  __shared__ float red[BMC][D];       // 16 KB reduction buffer

  const long R0 = (long)bh * S + (long)qt * BMC;

  for (int i = t; i < BMC * 64; i += 256)
    pk[(i >> 6) * 65 + (i & 63)] = packed[(R0 + (i >> 6)) * 64 + (i & 63)];
  // zero red while staging is in flight
  for (int i = t; i < BMC * D / 4; i += 256)
    *(f32x4*)&red[(i * 4) / D][(i * 4) % D] = f32x4{0.f, 0.f, 0.f, 0.f};
  __syncthreads();

  if (t < BMC) {
    int c = 0;
#pragma unroll
    for (int i = 0; i < 64; ++i) c += __popc(pk[t * 65 + i]);
    invs[t] = (c > 0) ? (1.0f / (float)c) : 0.0f;
  }

  const uint8_t* pkb = (const uint8_t*)pk;
  const uint8_t* ap[4];
#pragma unroll
  for (int mt = 0; mt < 4; ++mt)
    ap[mt] = pkb + (mt * 16 + l15) * 260 + lk;
  const __bf16* vt0 = VT + ((long)bh * 64) * 64 * 32 + (long)l15 * 32 + lk * 8;
  const float* vf0 = V + (long)bh * S * D + (long)lk * 8 * D + l15;

  f32x4 acc[4][4];
#pragma unroll
  for (int a = 0; a < 4; ++a)
#pragma unroll
    for (int b = 0; b < 4; ++b) acc[a][b] = f32x4{0.f, 0.f, 0.f, 0.f};

  auto LOADB = [&](bf16x8* dst, uint32_t* by, int kk) {
    if (USE_VT) {
#pragma unroll
      for (int n4 = 0; n4 < 4; ++n4)
        dst[n4] = *reinterpret_cast<const bf16x8*>(vt0 + ((long)kk * 64 + n4 * 16) * 32);
    } else {
      const float* vp = vf0 + (long)kk * 32 * D;
#pragma unroll
      for (int n4 = 0; n4 < 4; ++n4) {
        bf16x8 x;
#pragma unroll
        for (int j = 0; j < 8; ++j) x[j] = (__bf16)vp[j * D + n4 * 16];
        dst[n4] = x;
      }
    }
#pragma unroll
    for (int mt = 0; mt < 4; ++mt) by[mt] = ap[mt][kk * 4];
  };

  auto COMPUTE = [&](const bf16x8* bf, const uint32_t* by) {
#pragma unroll
    for (int mt = 0; mt < 4; ++mt) {
      union { uint32_t u[4]; bf16x8 v; } am;
#pragma unroll
      for (int p = 0; p < 4; ++p) {
        am.u[p] = (((by[mt] >> (2 * p)) & 1u) ? 0x3F80u : 0u)
                | (((by[mt] >> (2 * p + 1)) & 1u) ? 0x3F800000u : 0u);
      }
#pragma unroll
      for (int n4 = 0; n4 < 4; ++n4)
        acc[mt][n4] = __builtin_amdgcn_mfma_f32_16x16x32_bf16(am.v, bf[n4], acc[mt][n4], 0, 0, 0);
    }
  };

  const int k0 = w * 16;              // this wave's K-quarter (16 steps)
  bf16x8 bA[4], bB[4];
  uint32_t byA[4], byB[4];
  LOADB(bA, byA, k0);
#pragma unroll 1
  for (int kk = k0; kk < k0 + 16; kk += 2) {
    LOADB(bB, byB, kk + 1);
    COMPUTE(bA, byA);
    if (kk + 2 < k0 + 16) LOADB(bA, byA, kk + 2);
    COMPUTE(bB, byB);
  }

  // partial acc -> LDS reduce (C/D layout: row=mt*16+lk*4+ri, col=n4*16+l15)
#pragma unroll
  for (int mt = 0; mt < 4; ++mt)
#pragma unroll
    for (int ri = 0; ri < 4; ++ri)
#pragma unroll
      for (int n4 = 0; n4 < 4; ++n4)
        atomicAdd(&red[mt * 16 + lk * 4 + ri][n4 * 16 + l15], acc[mt][n4][ri]);
  __syncthreads();

  // cooperative scaled write: thread t -> 4 f32x4 (coalesced)
#pragma unroll
  for (int q = 0; q < 4; ++q) {
    const int idx = t * 4 + q;          // f32x4 index 0..1023
    const int row = idx >> 4;           // /16
    const int c4 = (idx & 15) * 4;
    const float iv = invs[row];
    f32x4 v = *(const f32x4*)&red[row][c4];
    v[0] *= iv; v[1] *= iv; v[2] *= iv; v[3] *= iv;
    __builtin_nontemporal_store(v, (f32x4*)(ctx + (R0 + row) * D + c4));
  }
}

extern "C" void kernel_launch(void* const* d_in, const int* in_sizes, int n_in,
                              void* d_out, int out_size, void* d_ws, size_t ws_size,
                              hipStream_t stream) {
  (void)in_sizes; (void)n_in; (void)out_size;
  const float* V = (const float*)d_in[2];           // Q,K provably unused (mask overwrites all scores)
  const int* mask = (const int*)d_in[3];
  float* ctx = (float*)d_out;                       // output 0: [B,H,S,D]
  float* attn = (float*)d_out + (size_t)CTX_ELEMS;  // output 1: [B,H,S,S]
  uint32_t* packed = (uint32_t*)d_out;              // scratch aliasing ctx region (tile-local)
  __bf16* VT = (__bf16*)d_ws;

  const int use_vt = (ws_size >= VT_BYTES) ? 1 : 0;
  k_mask<<<NVTB + NSTB, 256, 0, stream>>>(mask, V, attn, packed, VT, use_vt);
  if (use_vt)
    k_ctx<true><<<NROWS / BMC, 256, 0, stream>>>(packed, V, VT, ctx);
  else
    k_ctx<false><<<NROWS / BMC, 256, 0, stream>>>(packed, V, VT, ctx);
}

// Round 12
// 280.847 us; speedup vs baseline: 6.8946x; 1.0747x over previous
//
#include <hip/hip_runtime.h>
#include <hip/hip_bf16.h>
#include <stdint.h>

#define S 2048
#define D 64
#define BH 32
#define NROWS (BH * S)              // 65536
#define CTX_ELEMS (NROWS * D)
#define TR 32                       // rows per block (tile)
#define NTB (NROWS / TR)            // 2048 blocks -> 8/CU, 32 waves/CU

typedef __attribute__((ext_vector_type(8))) __bf16 bf16x8;
typedef __attribute__((ext_vector_type(4))) float f32x4;
typedef __attribute__((ext_vector_type(4))) int   i32x4;

// Single fused kernel at FULL streaming occupancy (the config R2/R4 never had).
// Block = 32 rows of one (b,h); 4 waves.
//  produce: wave w streams rows [w*8, w*8+8) (R8-proven wave-per-row body:
//           nt mask loads -> nib, butterfly cnt, nt attn stores, packed word
//           -> LDS pk). Bits never touch HBM.
//  consume: one barrier, then each wave does m-tile (w>>1), n-half (w&1):
//           2 MFMA per K-step, 64 steps; A from LDS bytes, B = f32 gather
//           from L2-resident V; acc = 2 f32x4 (VGPR-light).
// GEMM latency (~8us/wave) hides under other blocks' streaming (32 waves/CU).
__global__ __launch_bounds__(256, 8) void k_fused(const int* __restrict__ mask,
                                                  const float* __restrict__ V,
                                                  float* __restrict__ ctx,
                                                  float* __restrict__ attn) {
  const int t = threadIdx.x;
  const int lane = t & 63;
  const int w = t >> 6;               // wave 0..3

  __shared__ uint32_t pk[TR * 65];    // byte stride 260 -> conflict-free reads
  __shared__ float invs[TR];

  // XCD swizzle: XCD c owns 256 consecutive tiles = 4 whole (b,h) -> V L2-resident
  const int flat = blockIdx.x;
  const int wid = (flat & 7) * (NTB / 8) + (flat >> 3);
  const int bh = wid >> 6;            // 64 tiles per (b,h)
  const long R0 = (long)wid * TR;

  // ================= produce: 8 rows per wave =================
#pragma unroll 1
  for (int rr = 0; rr < 8; ++rr) {
    const int r = w * 8 + rr;
    const int* mrow = mask + (R0 + r) * (long)S;

    uint32_t nib = 0;
#pragma unroll
    for (int j = 0; j < 8; ++j) {
      const i32x4 m = __builtin_nontemporal_load(
          (const i32x4*)(mrow + j * 256 + lane * 4));
      nib |= (m[0] == 0 ? 1u : 0u) << (j * 4);
      nib |= (m[1] == 0 ? 1u : 0u) << (j * 4 + 1);
      nib |= (m[2] == 0 ? 1u : 0u) << (j * 4 + 2);
      nib |= (m[3] == 0 ? 1u : 0u) << (j * 4 + 3);
    }

    int cnt = __popc(nib);
#pragma unroll
    for (int off = 1; off < 64; off <<= 1) cnt += __shfl_xor(cnt, off, 64);
    const float inv = (cnt > 0) ? (1.0f / (float)cnt) : 0.0f;
    if (lane == 0) invs[r] = inv;

    float* arow = attn + (R0 + r) * (long)S;
#pragma unroll
    for (int j = 0; j < 8; ++j) {
      f32x4 a;
      a[0] = ((nib >> (j * 4)) & 1u)     ? inv : 0.0f;
      a[1] = ((nib >> (j * 4 + 1)) & 1u) ? inv : 0.0f;
      a[2] = ((nib >> (j * 4 + 2)) & 1u) ? inv : 0.0f;
      a[3] = ((nib >> (j * 4 + 3)) & 1u) ? inv : 0.0f;
      __builtin_nontemporal_store(a, (f32x4*)(arow + j * 256 + lane * 4));
    }

    // packed word l covers k=[l*32,l*32+32): bit i = nibble bit (i&3) of
    // group (l>>3) from lane (l&7)*8 + (i>>2)   (R8-proven shuffle)
    uint32_t word = 0;
    const int jsel = 4 * (lane >> 3);
    const int lbase = (lane & 7) * 8;
#pragma unroll
    for (int d = 0; d < 8; ++d) {
      const uint32_t nw = (uint32_t)__shfl((int)nib, lbase + d, 64);
      word |= ((nw >> jsel) & 0xFu) << (4 * d);
    }
    pk[r * 65 + lane] = word;
  }
  __syncthreads();

  // ================= consume: ctx = inv * (bits @ V) =================
  const int mt = w >> 1;              // m-tile 0..1 (rows mt*16..+16)
  const int nb = (w & 1) * 2;         // n4 pair: {nb, nb+1}
  const int l15 = lane & 15;
  const int lk = lane >> 4;           // 0..3

  const uint8_t* ap = ((const uint8_t*)pk) + (mt * 16 + l15) * 260 + lk;
  const float* vf0 = V + (long)bh * S * D + (long)lk * 8 * D + l15;

  f32x4 acc0 = f32x4{0.f, 0.f, 0.f, 0.f};
  f32x4 acc1 = f32x4{0.f, 0.f, 0.f, 0.f};

#pragma unroll 1
  for (int kk = 0; kk < S / 32; ++kk) {
    const float* vp = vf0 + (long)kk * 32 * D;
    bf16x8 b0, b1;
#pragma unroll
    for (int j = 0; j < 8; ++j) {
      b0[j] = (__bf16)vp[j * D + nb * 16];
      b1[j] = (__bf16)vp[j * D + (nb + 1) * 16];
    }
    const uint32_t by = ap[kk * 4];
    union { uint32_t u[4]; bf16x8 v; } am;
#pragma unroll
    for (int p = 0; p < 4; ++p) {
      am.u[p] = (((by >> (2 * p)) & 1u) ? 0x3F80u : 0u)
              | (((by >> (2 * p + 1)) & 1u) ? 0x3F800000u : 0u);
    }
    acc0 = __builtin_amdgcn_mfma_f32_16x16x32_bf16(am.v, b0, acc0, 0, 0, 0);
    acc1 = __builtin_amdgcn_mfma_f32_16x16x32_bf16(am.v, b1, acc1, 0, 0, 0);
  }

  // epilogue: C/D layout col=l15, row=lk*4+ri (m89-verified)
#pragma unroll
  for (int ri = 0; ri < 4; ++ri) {
    const int r = mt * 16 + lk * 4 + ri;
    const float iv = invs[r];
    const long orow = R0 + r;
    ctx[orow * D + nb * 16 + l15]       = acc0[ri] * iv;
    ctx[orow * D + (nb + 1) * 16 + l15] = acc1[ri] * iv;
  }
}

extern "C" void kernel_launch(void* const* d_in, const int* in_sizes, int n_in,
                              void* d_out, int out_size, void* d_ws, size_t ws_size,
                              hipStream_t stream) {
  (void)in_sizes; (void)n_in; (void)out_size; (void)d_ws; (void)ws_size;
  const float* V = (const float*)d_in[2];           // Q,K provably unused (mask overwrites all scores)
  const int* mask = (const int*)d_in[3];
  float* ctx = (float*)d_out;                       // output 0: [B,H,S,D]
  float* attn = (float*)d_out + (size_t)CTX_ELEMS;  // output 1: [B,H,S,S]

  k_fused<<<NTB, 256, 0, stream>>>(mask, V, ctx, attn);
}